// Round 4
// baseline (342.133 us; speedup 1.0000x reference)
//
#include <hip/hip_runtime.h>

#define HW 192
#define DD 512
#define GG 64
#define PP 64
#define NSTAGE 3

typedef __attribute__((ext_vector_type(8))) short short8_t;
typedef __attribute__((ext_vector_type(4))) float floatx4;

typedef __attribute__((address_space(3))) unsigned int lds_u32;
typedef const __attribute__((address_space(1))) unsigned int glb_u32;

__device__ __forceinline__ void gload_lds16(const void* g, void* l) {
  __builtin_amdgcn_global_load_lds((glb_u32*)g, (lds_u32*)l, 16, 0, 0);
}

__device__ __forceinline__ unsigned short f2bf(float f) {
  unsigned int u = __float_as_uint(f);
  u += 0x7fffu + ((u >> 16) & 1u);
  return (unsigned short)(u >> 16);
}

// Single-pass L2-normalize + transpose + bf16 cast.
// Block = (slab, 16-pos chunk), 512 threads. Pass-1: float4 reads (full 64B
// lines, 4 vmem insts/thread). ssq partials in padded LDS (conflict-free
// reduction). Pass-2: writes out[pos][c] coalesced as ushort2.
__global__ __launch_bounds__(512, 2) void norm_kernel(
    const float* __restrict__ gal, const float* __restrict__ prob,
    unsigned short* __restrict__ ws) {
  int b = blockIdx.x;  // 0..1535
  int s = b / 12;      // slab 0..127
  int q = b - s * 12;  // pos chunk 0..11
  const float* in = (s < GG) ? (gal + (size_t)s * DD * HW)
                             : (prob + (size_t)(s - GG) * DD * HW);
  unsigned short* out = ws + (size_t)s * DD * HW;
  int pos0 = q * 16;
  int t = threadIdx.x;
  int cq = t >> 2;    // 0..127
  int quad = t & 3;   // 0..3

  __shared__ float T[16 * 518];     // 33.2 KB, layout [pos][c] pad 518
  __shared__ float sqa[128][17];    // 8.7 KB, padded: conflict-free reduce
  __shared__ float scl[16];

  float p0 = 0.f, p1 = 0.f, p2 = 0.f, p3 = 0.f;
#pragma unroll
  for (int cb = 0; cb < 4; ++cb) {
    int c = cb * 128 + cq;
    const float4 v = *(const float4*)(in + (size_t)c * HW + pos0 + quad * 4);
    int pp = quad * 4;
    T[(pp + 0) * 518 + c] = v.x;
    T[(pp + 1) * 518 + c] = v.y;
    T[(pp + 2) * 518 + c] = v.z;
    T[(pp + 3) * 518 + c] = v.w;
    p0 += v.x * v.x; p1 += v.y * v.y; p2 += v.z * v.z; p3 += v.w * v.w;
  }
  sqa[cq][quad * 4 + 0] = p0;
  sqa[cq][quad * 4 + 1] = p1;
  sqa[cq][quad * 4 + 2] = p2;
  sqa[cq][quad * 4 + 3] = p3;
  __syncthreads();
  if (t < 16) {
    float v = 0.f;
    for (int k = 0; k < 128; ++k) v += sqa[k][t];
    scl[t] = 1.f / fmaxf(sqrtf(v), 1e-12f);
  }
  __syncthreads();
#pragma unroll
  for (int k = 0; k < 8; ++k) {
    int idx2 = (t + k * 512) * 2;
    int c = idx2 & 511;
    int pp2 = idx2 >> 9;  // 0..15
    float sc = scl[pp2];
    float a = T[pp2 * 518 + c] * sc;
    float bb = T[pp2 * 518 + c + 1] * sc;
    unsigned int pk = ((unsigned)f2bf(bb) << 16) | (unsigned)f2bf(a);
    *(unsigned int*)&out[(size_t)(pos0 + pp2) * DD + c] = pk;
  }
}

// One block per (g,p). Producer/consumer wave specialization:
// waves 0-3 = consumers (96x96 MFMA tiles), waves 4-7 = producers streaming a
// 3-stage LDS ring via global_load_lds. Flag-counter sync (no __syncthreads
// in the K-loop) so the four pipes (MFMA / LDS / L2 / TA) overlap instead of
// serializing at a per-kb barrier (r3: serial sum 4000 cyc/kb vs max 1400).
__global__ __launch_bounds__(512, 2) void qaconv_gemm(
    const unsigned short* __restrict__ ws, const float* __restrict__ fcw,
    const float* __restrict__ bnw, const float* __restrict__ bnb,
    const float* __restrict__ bnm, const float* __restrict__ bnv,
    const float* __restrict__ fcb, const float* __restrict__ lw,
    const float* __restrict__ lb, const float* __restrict__ lm,
    const float* __restrict__ lv, float* __restrict__ out) {
  int bid = blockIdx.x;
  int sb = bid >> 6, li = bid & 63;  // 8x8 supertiles for L2 locality
  int g = ((sb >> 3) << 3) + (li >> 3);
  int p = ((sb & 7) << 3) + (li & 7);
  const unsigned short* Bsrc = ws + (size_t)g * DD * HW;         // galt[g][j][c]
  const unsigned short* Asrc = ws + (size_t)(GG + p) * DD * HW;  // kern[p][i][c]

  // LDS slot n = row*4 + (kc ^ ((row>>1)&3)), 16B per slot
  __shared__ unsigned short A_lds[NSTAGE][768 * 8];  // 3 x 12 KB
  __shared__ unsigned short B_lds[NSTAGE][768 * 8];  // 3 x 12 KB
  __shared__ float colpart[2][HW];
  __shared__ float rowpart[2][HW];
  __shared__ float redbuf[8][2];
  __shared__ int rdy[NSTAGE];  // producer completions per stage (monotonic)
  __shared__ int fin[NSTAGE];  // consumer completions per stage (monotonic)

  int tid = threadIdx.x;
  int lane = tid & 63;
  int wave = tid >> 6;

  if (tid < NSTAGE) { rdy[tid] = 0; fin[tid] = 0; }
  __syncthreads();

  if (wave >= 4) {
    // ---------------- producers ----------------
    int pw = wave - 4;  // 0..3: {0,1}->A halves, {2,3}->B halves
    const unsigned short* src = (pw < 2) ? Asrc : Bsrc;
    unsigned short(*dst)[768 * 8] = (pw < 2) ? A_lds : B_lds;
    int base = (pw & 1) * 384;
    int ns[6];
    size_t goffs[6];
#pragma unroll
    for (int s = 0; s < 6; ++s) {
      int n = base + s * 64 + lane;
      int row = n >> 2;
      int kc = (n & 3) ^ ((n >> 3) & 3);
      ns[s] = n;
      goffs[s] = (size_t)row * DD + (size_t)(kc * 8);
    }
    for (int kb = 0; kb < DD / 32; ++kb) {
      int st = kb % NSTAGE;
      if (kb >= NSTAGE) {
        int target = 4 * (kb / NSTAGE);  // prior occupant fully consumed
        volatile int* f = &fin[st];
        while (*f < target) {}
      }
#pragma unroll
      for (int s = 0; s < 6; ++s)
        gload_lds16(src + goffs[s] + (size_t)(kb * 32), &dst[st][ns[s] * 8]);
      __builtin_amdgcn_s_waitcnt(0x0F70);  // vmcnt(0): DMA landed in LDS
      if (lane == 0) atomicAdd(&rdy[st], 1);
    }
    // fall through to epilogue barrier
    float zpart = 0.f;
    if (lane == 0) { redbuf[wave][0] = 0.f; redbuf[wave][1] = 0.f; }
    (void)zpart;
  } else {
    // ---------------- consumers ----------------
    int wi = wave >> 1, wj = wave & 1;
    int l15 = lane & 15, l4 = lane >> 4;

    floatx4 acc[6][6];
#pragma unroll
    for (int a = 0; a < 6; ++a)
#pragma unroll
      for (int c = 0; c < 6; ++c) acc[a][c] = (floatx4){0.f, 0.f, 0.f, 0.f};

    int sw = l4 ^ ((l15 >> 1) & 3);
    int aBase = ((wi * 96 + l15) * 4 + sw) * 8;
    int bBase = ((wj * 96 + l15) * 4 + sw) * 8;

    for (int kb = 0; kb < DD / 32; ++kb) {
      int st = kb % NSTAGE;
      int target = 4 * (kb / NSTAGE + 1);
      {
        volatile int* f = &rdy[st];
        while (*f < target) {}
      }
      short8_t a[6];
#pragma unroll
      for (int it = 0; it < 6; ++it)
        a[it] = *(const short8_t*)&A_lds[st][aBase + it * 512];
#pragma unroll
      for (int jt = 0; jt < 6; ++jt) {
        short8_t b = *(const short8_t*)&B_lds[st][bBase + jt * 512];
#pragma unroll
        for (int it = 0; it < 6; ++it)
          acc[it][jt] = __builtin_amdgcn_mfma_f32_16x16x32_bf16(a[it], b, acc[it][jt], 0, 0, 0);
      }
      if (lane == 0) atomicAdd(&fin[st], 1);
    }

    // ---- epilogue: dual max-pool into LDS partials ----
    // C/D layout: i = wi*96 + it*16 + l4*4 + r ; j = wj*96 + jt*16 + l15
    float cm[6];
    float rm[6][4];
#pragma unroll
    for (int jt = 0; jt < 6; ++jt) cm[jt] = -3.4e38f;
#pragma unroll
    for (int it = 0; it < 6; ++it)
#pragma unroll
      for (int r = 0; r < 4; ++r) rm[it][r] = -3.4e38f;
#pragma unroll
    for (int it = 0; it < 6; ++it)
#pragma unroll
      for (int jt = 0; jt < 6; ++jt)
#pragma unroll
        for (int r = 0; r < 4; ++r) {
          float v = acc[it][jt][r];
          cm[jt] = fmaxf(cm[jt], v);
          rm[it][r] = fmaxf(rm[it][r], v);
        }
#pragma unroll
    for (int jt = 0; jt < 6; ++jt) {
      float v = cm[jt];
      v = fmaxf(v, __shfl_xor(v, 16, 64));
      v = fmaxf(v, __shfl_xor(v, 32, 64));
      if (lane < 16) colpart[wi][wj * 96 + jt * 16 + lane] = v;
    }
#pragma unroll
    for (int it = 0; it < 6; ++it)
#pragma unroll
      for (int r = 0; r < 4; ++r) {
        float v = rm[it][r];
        v = fmaxf(v, __shfl_xor(v, 1, 64));
        v = fmaxf(v, __shfl_xor(v, 2, 64));
        v = fmaxf(v, __shfl_xor(v, 4, 64));
        v = fmaxf(v, __shfl_xor(v, 8, 64));
        if (l15 == 0) rowpart[wj][wi * 96 + it * 16 + l4 * 4 + r] = v;
      }
  }
  __syncthreads();  // all 8 waves, exactly once

  // ---- fused BN -> fc -> lbn -> sigmoid ----
  float part = 0.f, wpart = 0.f;
  if (tid < HW) {
    float cmax = fmaxf(colpart[0][tid], colpart[1][tid]);  // score[j]
    float rmax = fmaxf(rowpart[0][tid], rowpart[1][tid]);  // score[192+i]
    float w1 = fcw[tid], w2 = fcw[HW + tid];
    part = cmax * w1 + rmax * w2;
    wpart = w1 + w2;
  }
#pragma unroll
  for (int off = 32; off > 0; off >>= 1) {
    part += __shfl_down(part, off, 64);
    wpart += __shfl_down(wpart, off, 64);
  }
  if (lane == 0) { redbuf[wave][0] = part; redbuf[wave][1] = wpart; }
  __syncthreads();
  if (tid == 0) {
    float s = 0.f, wsum = 0.f;
#pragma unroll
    for (int w = 0; w < 8; ++w) { s += redbuf[w][0]; wsum += redbuf[w][1]; }
    float bnA = bnw[0] * rsqrtf(bnv[0] + 1e-5f);
    float bnB = bnb[0] - bnm[0] * bnA;
    float sc = bnA * s + bnB * wsum + fcb[0];
    float lA = lw[0] * rsqrtf(lv[0] + 1e-5f);
    sc = (sc - lm[0]) * lA + lb[0];
    out[g * PP + p] = 1.f / (1.f + __expf(-sc * 0.1f));
  }
}

extern "C" void kernel_launch(void* const* d_in, const int* in_sizes, int n_in,
                              void* d_out, int out_size, void* d_ws, size_t ws_size,
                              hipStream_t stream) {
  const float* gal  = (const float*)d_in[0];
  const float* prob = (const float*)d_in[1];
  const float* bnw  = (const float*)d_in[2];
  const float* bnb  = (const float*)d_in[3];
  const float* bnm  = (const float*)d_in[4];
  const float* bnv  = (const float*)d_in[5];
  const float* fcw  = (const float*)d_in[6];
  const float* fcb  = (const float*)d_in[7];
  const float* lw   = (const float*)d_in[8];
  const float* lb   = (const float*)d_in[9];
  const float* lm   = (const float*)d_in[10];
  const float* lv   = (const float*)d_in[11];
  unsigned short* ws = (unsigned short*)d_ws;
  float* out = (float*)d_out;

  hipLaunchKernelGGL(norm_kernel, dim3(1536), dim3(512), 0, stream, gal, prob, ws);
  hipLaunchKernelGGL(qaconv_gemm, dim3(GG * PP), dim3(512), 0, stream, ws, fcw,
                     bnw, bnb, bnm, bnv, fcb, lw, lb, lm, lv, out);
}

// Round 5
// 270.878 us; speedup vs baseline: 1.2631x; 1.2631x over previous
//
#include <hip/hip_runtime.h>

#define HW 192
#define DD 512
#define GG 64
#define PP 64
#define SLAB 98304  // 192*512 fp8 bytes per slab

typedef __attribute__((ext_vector_type(4))) float floatx4;

typedef __attribute__((address_space(3))) unsigned int lds_u32;
typedef const __attribute__((address_space(1))) unsigned int glb_u32;

__device__ __forceinline__ void gload_lds16(const void* g, void* l) {
  __builtin_amdgcn_global_load_lds((glb_u32*)g, (lds_u32*)l, 16, 0, 0);
}

// L2-normalize over channels -> fp8 e4m3, K-major layout:
// ws[slab][kb][pos][32B] (kb = k-block of 32 channels). Block = (slab, 16-pos
// chunk), 512 threads. Pass A: float4 coalesced ssq. Pass B: re-read from
// L1/L2 (16-lane full-line groups), cvt_pk_fp8, one int4 store per thread.
__global__ __launch_bounds__(512, 2) void norm_kernel(
    const float* __restrict__ gal, const float* __restrict__ prob,
    unsigned char* __restrict__ ws) {
  int b = blockIdx.x;  // 0..1535
  int s = b / 12;      // slab 0..127
  int q = b - s * 12;  // pos chunk 0..11
  const float* in = (s < GG) ? (gal + (size_t)s * DD * HW)
                             : (prob + (size_t)(s - GG) * DD * HW);
  unsigned char* out = ws + (size_t)s * SLAB;
  int pos0 = q * 16;
  int t = threadIdx.x;

  __shared__ float sqa[128][17];
  __shared__ float sq2[16][17];
  __shared__ float scl[16];

  {
    int cq = t >> 2;   // 0..127
    int quad = t & 3;  // 0..3
    float p0 = 0.f, p1 = 0.f, p2 = 0.f, p3 = 0.f;
#pragma unroll
    for (int cb = 0; cb < 4; ++cb) {
      int c = cb * 128 + cq;
      const float4 v = *(const float4*)(in + (size_t)c * HW + pos0 + quad * 4);
      p0 += v.x * v.x; p1 += v.y * v.y; p2 += v.z * v.z; p3 += v.w * v.w;
    }
    sqa[cq][quad * 4 + 0] = p0;
    sqa[cq][quad * 4 + 1] = p1;
    sqa[cq][quad * 4 + 2] = p2;
    sqa[cq][quad * 4 + 3] = p3;
  }
  __syncthreads();
  if (t < 256) {
    int g = t >> 4, pos = t & 15;
    float v = 0.f;
#pragma unroll
    for (int r = 0; r < 8; ++r) v += sqa[g * 8 + r][pos];
    sq2[g][pos] = v;
  }
  __syncthreads();
  if (t < 16) {
    float v = 0.f;
#pragma unroll
    for (int r = 0; r < 16; ++r) v += sq2[r][t];
    scl[t] = 1.f / fmaxf(sqrtf(v), 1e-12f);
  }
  __syncthreads();

  {
    int kb = t >> 5;         // 0..15
    int pos = (t >> 1) & 15; // 0..15
    int h = t & 1;           // 0..1
    float sc = scl[pos];
    const float* src = in + (size_t)(kb * 32 + h * 16) * HW + pos0 + pos;
    float v[16];
#pragma unroll
    for (int k = 0; k < 16; ++k) v[k] = src[(size_t)k * HW] * sc;
    uint4 u;
    u.x = __builtin_amdgcn_cvt_pk_fp8_f32(v[0], v[1], 0, false);
    u.x = __builtin_amdgcn_cvt_pk_fp8_f32(v[2], v[3], u.x, true);
    u.y = __builtin_amdgcn_cvt_pk_fp8_f32(v[4], v[5], 0, false);
    u.y = __builtin_amdgcn_cvt_pk_fp8_f32(v[6], v[7], u.y, true);
    u.z = __builtin_amdgcn_cvt_pk_fp8_f32(v[8], v[9], 0, false);
    u.z = __builtin_amdgcn_cvt_pk_fp8_f32(v[10], v[11], u.z, true);
    u.w = __builtin_amdgcn_cvt_pk_fp8_f32(v[12], v[13], 0, false);
    u.w = __builtin_amdgcn_cvt_pk_fp8_f32(v[14], v[15], u.w, true);
    *(uint4*)(out + (size_t)kb * 6144 + (size_t)(pos0 + pos) * 32 + h * 16) = u;
  }
}

// One block per (g,p), fp8 e4m3, BK=64 double-buffered (r3 structure — best
// measured). K-major ws layout => each stage is one contiguous 12 KB region,
// full 64B lines, DMA lane-order trivial. 16B half-swizzle per 32B row keeps
// ds_read_b64 fragment reads 2-way on banks (free). Serial-sum model:
// MFMA 179k + LDS 72k + L2 55k + TA 49k cyc/CU => ~148 us predicted.
__global__ __launch_bounds__(256, 2) void qaconv_gemm(
    const unsigned char* __restrict__ ws, const float* __restrict__ fcw,
    const float* __restrict__ bnw, const float* __restrict__ bnb,
    const float* __restrict__ bnm, const float* __restrict__ bnv,
    const float* __restrict__ fcb, const float* __restrict__ lw,
    const float* __restrict__ lb, const float* __restrict__ lm,
    const float* __restrict__ lv, float* __restrict__ out) {
  int bid = blockIdx.x;
  int sb = bid >> 6, li = bid & 63;  // 8x8 supertiles for L2 locality
  int g = ((sb >> 3) << 3) + (li >> 3);
  int p = ((sb & 7) << 3) + (li & 7);
  const unsigned char* Bsrc = ws + (size_t)g * SLAB;         // galt[g][j][c]
  const unsigned char* Asrc = ws + (size_t)(GG + p) * SLAB;  // kern[p][i][c]

  __shared__ unsigned char A_lds[2][12288];  // [buf][kbsub(2)][row(192)][32B]
  __shared__ unsigned char B_lds[2][12288];
  __shared__ float colpart[2][HW];
  __shared__ float rowpart[2][HW];
  __shared__ float redbuf[4][2];

  int tid = threadIdx.x;
  int lane = tid & 63;
  int wave = tid >> 6;
  int wi = wave >> 1, wj = wave & 1;
  int l15 = lane & 15, l4 = lane >> 4;

  floatx4 acc[6][6];
#pragma unroll
  for (int a = 0; a < 6; ++a)
#pragma unroll
    for (int c = 0; c < 6; ++c) acc[a][c] = (floatx4){0.f, 0.f, 0.f, 0.f};

  // staging geometry: chunk m = tid + s*256 (s=0..2), covers both A and B.
  // global byte = (m>>1)*32 + ((m&1)^((m>>1)&1))*16 ; LDS byte = m*16
  int mIdx[3];
  int mOff[3];
#pragma unroll
  for (int s = 0; s < 3; ++s) {
    int m = tid + s * 256;
    mIdx[s] = m;
    mOff[s] = (m >> 1) * 32 + (((m & 1) ^ ((m >> 1) & 1)) << 4);
  }

#define STAGE(KB2, BUF)                                             \
  do {                                                              \
    _Pragma("unroll") for (int s_ = 0; s_ < 3; ++s_) {              \
      size_t go = (size_t)(KB2)*12288 + (size_t)mOff[s_];           \
      gload_lds16(Asrc + go, &A_lds[BUF][mIdx[s_] * 16]);           \
      gload_lds16(Bsrc + go, &B_lds[BUF][mIdx[s_] * 16]);           \
    }                                                               \
  } while (0)

  STAGE(0, 0);
  __syncthreads();

  // fragment offsets: row = w*96 + it*16 + l15 (row&1 == l15&1)
  // byte = kbsub*6144 + row*32 + hsel*16 + (l4&1)*8 ; hsel = (l4>>1)^(l15&1)
  int hsel = ((l4 >> 1) ^ (l15 & 1)) << 4;
  int q8 = (l4 & 1) << 3;
  int aB = (wi * 96 + l15) * 32 + hsel + q8;
  int bB = (wj * 96 + l15) * 32 + hsel + q8;

  for (int kb2 = 0; kb2 < 8; ++kb2) {
    int cur = kb2 & 1;
    if (kb2 < 7) STAGE(kb2 + 1, cur ^ 1);
#pragma unroll
    for (int ks = 0; ks < 2; ++ks) {
      long a[6];
#pragma unroll
      for (int it = 0; it < 6; ++it)
        a[it] = *(const long*)&A_lds[cur][ks * 6144 + aB + it * 512];
#pragma unroll
      for (int jt = 0; jt < 6; ++jt) {
        long b = *(const long*)&B_lds[cur][ks * 6144 + bB + jt * 512];
#pragma unroll
        for (int it = 0; it < 6; ++it)
          acc[it][jt] = __builtin_amdgcn_mfma_f32_16x16x32_fp8_fp8(a[it], b, acc[it][jt], 0, 0, 0);
      }
    }
    __syncthreads();
  }
#undef STAGE

  // ---- epilogue: dual max-pool ----
  // C/D layout: i = wi*96 + it*16 + l4*4 + r ; j = wj*96 + jt*16 + l15
  float cm[6];
  float rm[6][4];
#pragma unroll
  for (int jt = 0; jt < 6; ++jt) cm[jt] = -3.4e38f;
#pragma unroll
  for (int it = 0; it < 6; ++it)
#pragma unroll
    for (int r = 0; r < 4; ++r) rm[it][r] = -3.4e38f;
#pragma unroll
  for (int it = 0; it < 6; ++it)
#pragma unroll
    for (int jt = 0; jt < 6; ++jt)
#pragma unroll
      for (int r = 0; r < 4; ++r) {
        float v = acc[it][jt][r];
        cm[jt] = fmaxf(cm[jt], v);
        rm[it][r] = fmaxf(rm[it][r], v);
      }

#pragma unroll
  for (int jt = 0; jt < 6; ++jt) {
    float v = cm[jt];
    v = fmaxf(v, __shfl_xor(v, 16, 64));
    v = fmaxf(v, __shfl_xor(v, 32, 64));
    if (lane < 16) colpart[wi][wj * 96 + jt * 16 + lane] = v;
  }
#pragma unroll
  for (int it = 0; it < 6; ++it)
#pragma unroll
    for (int r = 0; r < 4; ++r) {
      float v = rm[it][r];
      v = fmaxf(v, __shfl_xor(v, 1, 64));
      v = fmaxf(v, __shfl_xor(v, 2, 64));
      v = fmaxf(v, __shfl_xor(v, 4, 64));
      v = fmaxf(v, __shfl_xor(v, 8, 64));
      if (l15 == 0) rowpart[wj][wi * 96 + it * 16 + l4 * 4 + r] = v;
    }
  __syncthreads();

  // ---- fused BN -> fc -> lbn -> sigmoid ----
  float part = 0.f, wpart = 0.f;
  if (tid < HW) {
    float cmax = fmaxf(colpart[0][tid], colpart[1][tid]);  // score[j]
    float rmax = fmaxf(rowpart[0][tid], rowpart[1][tid]);  // score[192+i]
    float w1 = fcw[tid], w2 = fcw[HW + tid];
    part = cmax * w1 + rmax * w2;
    wpart = w1 + w2;
  }
#pragma unroll
  for (int off = 32; off > 0; off >>= 1) {
    part += __shfl_down(part, off, 64);
    wpart += __shfl_down(wpart, off, 64);
  }
  if (lane == 0) { redbuf[wave][0] = part; redbuf[wave][1] = wpart; }
  __syncthreads();
  if (tid == 0) {
    float s = redbuf[0][0] + redbuf[1][0] + redbuf[2][0] + redbuf[3][0];
    float wsum = redbuf[0][1] + redbuf[1][1] + redbuf[2][1] + redbuf[3][1];
    float bnA = bnw[0] * rsqrtf(bnv[0] + 1e-5f);
    float bnB = bnb[0] - bnm[0] * bnA;
    float sc = bnA * s + bnB * wsum + fcb[0];
    float lA = lw[0] * rsqrtf(lv[0] + 1e-5f);
    sc = (sc - lm[0]) * lA + lb[0];
    out[g * PP + p] = 1.f / (1.f + __expf(-sc * 0.1f));
  }
}

extern "C" void kernel_launch(void* const* d_in, const int* in_sizes, int n_in,
                              void* d_out, int out_size, void* d_ws, size_t ws_size,
                              hipStream_t stream) {
  const float* gal  = (const float*)d_in[0];
  const float* prob = (const float*)d_in[1];
  const float* bnw  = (const float*)d_in[2];
  const float* bnb  = (const float*)d_in[3];
  const float* bnm  = (const float*)d_in[4];
  const float* bnv  = (const float*)d_in[5];
  const float* fcw  = (const float*)d_in[6];
  const float* fcb  = (const float*)d_in[7];
  const float* lw   = (const float*)d_in[8];
  const float* lb   = (const float*)d_in[9];
  const float* lm   = (const float*)d_in[10];
  const float* lv   = (const float*)d_in[11];
  unsigned char* ws = (unsigned char*)d_ws;
  float* out = (float*)d_out;

  hipLaunchKernelGGL(norm_kernel, dim3(1536), dim3(512), 0, stream, gal, prob, ws);
  hipLaunchKernelGGL(qaconv_gemm, dim3(GG * PP), dim3(256), 0, stream, ws, fcw,
                     bnw, bnb, bnm, bnv, fcb, lw, lb, lm, lv, out);
}

// Round 6
// 229.939 us; speedup vs baseline: 1.4879x; 1.1780x over previous
//
#include <hip/hip_runtime.h>

#define HW 192
#define DD 512
#define GG 64
#define PP 64
#define SLAB 98304  // 192*512 fp8 bytes per slab

typedef __attribute__((ext_vector_type(4))) float floatx4;
typedef __attribute__((ext_vector_type(2))) long long2_t;

typedef __attribute__((address_space(3))) unsigned int lds_u32;
typedef const __attribute__((address_space(1))) unsigned int glb_u32;

__device__ __forceinline__ void gload_lds16(const void* g, void* l) {
  __builtin_amdgcn_global_load_lds((glb_u32*)g, (lds_u32*)l, 16, 0, 0);
}

// L2-normalize over channels -> fp8 e4m3. Single global read via LDS fp32
// tile. ws layout per slab: [kb2(8)][row(192)][kc(4)][16B], the 16B chunk =
// [ks0: ch kb2*64+kc*8+0..8 | ks1: ch kb2*64+32+kc*8+0..8] so one GEMM
// ds_read_b128 fetches both K=32 fragments. T pad 524 words => every LDS
// access pattern here is <=2-way on banks (free).
__global__ __launch_bounds__(512, 2) void norm_kernel(
    const float* __restrict__ gal, const float* __restrict__ prob,
    unsigned char* __restrict__ ws) {
  int b = blockIdx.x;  // 0..1535
  int s = b / 12;      // slab 0..127
  int q = b - s * 12;  // pos chunk 0..11
  const float* in = (s < GG) ? (gal + (size_t)s * DD * HW)
                             : (prob + (size_t)(s - GG) * DD * HW);
  unsigned char* out = ws + (size_t)s * SLAB;
  int pos0 = q * 16;
  int t = threadIdx.x;

  __shared__ float T[16][524];   // 33.5 KB, [pos][c]
  __shared__ float sqa[128][17];
  __shared__ float sq2[16][17];
  __shared__ float scl[16];

  {
    int cq = t >> 2;   // 0..127
    int quad = t & 3;  // 0..3
    float p0 = 0.f, p1 = 0.f, p2 = 0.f, p3 = 0.f;
#pragma unroll
    for (int cb = 0; cb < 4; ++cb) {
      int c = cb * 128 + cq;
      const float4 v = *(const float4*)(in + (size_t)c * HW + pos0 + quad * 4);
      T[quad * 4 + 0][c] = v.x;
      T[quad * 4 + 1][c] = v.y;
      T[quad * 4 + 2][c] = v.z;
      T[quad * 4 + 3][c] = v.w;
      p0 += v.x * v.x; p1 += v.y * v.y; p2 += v.z * v.z; p3 += v.w * v.w;
    }
    sqa[cq][quad * 4 + 0] = p0;
    sqa[cq][quad * 4 + 1] = p1;
    sqa[cq][quad * 4 + 2] = p2;
    sqa[cq][quad * 4 + 3] = p3;
  }
  __syncthreads();
  if (t < 256) {
    int g2 = t >> 4, pos = t & 15;
    float v = 0.f;
#pragma unroll
    for (int r = 0; r < 8; ++r) v += sqa[g2 * 8 + r][pos];
    sq2[g2][pos] = v;
  }
  __syncthreads();
  if (t < 16) {
    float v = 0.f;
#pragma unroll
    for (int r = 0; r < 16; ++r) v += sq2[r][t];
    scl[t] = 1.f / fmaxf(sqrtf(v), 1e-12f);
  }
  __syncthreads();

  {
    int kc = t & 3;          // 0..3
    int pos = (t >> 2) & 15; // 0..15
    int kb2 = t >> 6;        // 0..7
    float sc = scl[pos];
    int base = kb2 * 64 + kc * 8;
    const float4 r0 = *(const float4*)&T[pos][base + 0];
    const float4 r1 = *(const float4*)&T[pos][base + 4];
    const float4 r2 = *(const float4*)&T[pos][base + 32];
    const float4 r3 = *(const float4*)&T[pos][base + 36];
    uint4 u;
    u.x = __builtin_amdgcn_cvt_pk_fp8_f32(r0.x * sc, r0.y * sc, 0, false);
    u.x = __builtin_amdgcn_cvt_pk_fp8_f32(r0.z * sc, r0.w * sc, u.x, true);
    u.y = __builtin_amdgcn_cvt_pk_fp8_f32(r1.x * sc, r1.y * sc, 0, false);
    u.y = __builtin_amdgcn_cvt_pk_fp8_f32(r1.z * sc, r1.w * sc, u.y, true);
    u.z = __builtin_amdgcn_cvt_pk_fp8_f32(r2.x * sc, r2.y * sc, 0, false);
    u.z = __builtin_amdgcn_cvt_pk_fp8_f32(r2.z * sc, r2.w * sc, u.z, true);
    u.w = __builtin_amdgcn_cvt_pk_fp8_f32(r3.x * sc, r3.y * sc, 0, false);
    u.w = __builtin_amdgcn_cvt_pk_fp8_f32(r3.z * sc, r3.w * sc, u.w, true);
    *(uint4*)(out + (size_t)kb2 * 12288 + (size_t)(pos0 + pos) * 64 + kc * 16) = u;
  }
}

// One block per (g,p), fp8 e4m3, BK=64 double-buffered. Fragment reads are
// ds_read_b128 fetching BOTH K=32 sub-fragments (ws chunk pairing), with the
// r3-proven XOR swizzle (l4 ^ ((l15>>1)&3)) => every b128 16-lane phase
// covers all 8 bank-slots at 2 lanes each = conflict-free (r5's b64 pattern
// was 4-way conflicted: 3.78e7 SQ_LDS_BANK_CONFLICT = 36% of cycles).
__global__ __launch_bounds__(256, 2) void qaconv_gemm(
    const unsigned char* __restrict__ ws, const float* __restrict__ fcw,
    const float* __restrict__ bnw, const float* __restrict__ bnb,
    const float* __restrict__ bnm, const float* __restrict__ bnv,
    const float* __restrict__ fcb, const float* __restrict__ lw,
    const float* __restrict__ lb, const float* __restrict__ lm,
    const float* __restrict__ lv, float* __restrict__ out) {
  int bid = blockIdx.x;
  int sb = bid >> 6, li = bid & 63;  // 8x8 supertiles for L2 locality
  int g = ((sb >> 3) << 3) + (li >> 3);
  int p = ((sb & 7) << 3) + (li & 7);
  const unsigned char* Bsrc = ws + (size_t)g * SLAB;         // galt[g][j][c]
  const unsigned char* Asrc = ws + (size_t)(GG + p) * SLAB;  // kern[p][i][c]

  __shared__ unsigned char A_lds[2][12288];  // [buf][row(192)][slot(4)][16B]
  __shared__ unsigned char B_lds[2][12288];
  __shared__ float colpart[2][HW];
  __shared__ float rowpart[2][HW];
  __shared__ float redbuf[4][2];

  int tid = threadIdx.x;
  int lane = tid & 63;
  int wave = tid >> 6;
  int wi = wave >> 1, wj = wave & 1;
  int l15 = lane & 15, l4 = lane >> 4;

  floatx4 acc[6][6];
#pragma unroll
  for (int a = 0; a < 6; ++a)
#pragma unroll
    for (int c = 0; c < 6; ++c) acc[a][c] = (floatx4){0.f, 0.f, 0.f, 0.f};

  // staging: chunk m -> LDS byte m*16; global = row*64 + (slot^s(row))*16,
  // row = m>>2, slot = m&3, s(row) = (row>>1)&3 = (m>>3)&3.
  // 4 consecutive lanes = one full 64B line (perfectly coalesced).
  int mIdx[3];
  int mOff[3];
#pragma unroll
  for (int s = 0; s < 3; ++s) {
    int m = tid + s * 256;
    mIdx[s] = m;
    mOff[s] = (m >> 2) * 64 + ((((m & 3) ^ ((m >> 3) & 3))) << 4);
  }

#define STAGE(KB2, BUF)                                             \
  do {                                                              \
    _Pragma("unroll") for (int s_ = 0; s_ < 3; ++s_) {              \
      size_t go = (size_t)(KB2)*12288 + (size_t)mOff[s_];           \
      gload_lds16(Asrc + go, &A_lds[BUF][mIdx[s_] * 16]);           \
      gload_lds16(Bsrc + go, &B_lds[BUF][mIdx[s_] * 16]);           \
    }                                                               \
  } while (0)

  STAGE(0, 0);
  __syncthreads();

  // fragment b128: row = w*96 + it*16 + l15; addr = row*64 + (l4^((l15>>1)&3))*16
  int sw = (l4 ^ ((l15 >> 1) & 3)) << 4;
  int aB = (wi * 96 + l15) * 64 + sw;
  int bB = (wj * 96 + l15) * 64 + sw;

  for (int kb2 = 0; kb2 < 8; ++kb2) {
    int cur = kb2 & 1;
    if (kb2 < 7) STAGE(kb2 + 1, cur ^ 1);

    long2_t a2[6];
#pragma unroll
    for (int it = 0; it < 6; ++it)
      a2[it] = *(const long2_t*)&A_lds[cur][aB + it * 1024];
#pragma unroll
    for (int jt = 0; jt < 6; ++jt) {
      long2_t b2 = *(const long2_t*)&B_lds[cur][bB + jt * 1024];
#pragma unroll
      for (int it = 0; it < 6; ++it)
        acc[it][jt] = __builtin_amdgcn_mfma_f32_16x16x32_fp8_fp8(a2[it].x, b2.x, acc[it][jt], 0, 0, 0);
#pragma unroll
      for (int it = 0; it < 6; ++it)
        acc[it][jt] = __builtin_amdgcn_mfma_f32_16x16x32_fp8_fp8(a2[it].y, b2.y, acc[it][jt], 0, 0, 0);
    }
    __syncthreads();
  }
#undef STAGE

  // ---- epilogue: dual max-pool ----
  // C/D layout: i = wi*96 + it*16 + l4*4 + r ; j = wj*96 + jt*16 + l15
  float cm[6];
  float rm[6][4];
#pragma unroll
  for (int jt = 0; jt < 6; ++jt) cm[jt] = -3.4e38f;
#pragma unroll
  for (int it = 0; it < 6; ++it)
#pragma unroll
    for (int r = 0; r < 4; ++r) rm[it][r] = -3.4e38f;
#pragma unroll
  for (int it = 0; it < 6; ++it)
#pragma unroll
    for (int jt = 0; jt < 6; ++jt)
#pragma unroll
      for (int r = 0; r < 4; ++r) {
        float v = acc[it][jt][r];
        cm[jt] = fmaxf(cm[jt], v);
        rm[it][r] = fmaxf(rm[it][r], v);
      }

#pragma unroll
  for (int jt = 0; jt < 6; ++jt) {
    float v = cm[jt];
    v = fmaxf(v, __shfl_xor(v, 16, 64));
    v = fmaxf(v, __shfl_xor(v, 32, 64));
    if (lane < 16) colpart[wi][wj * 96 + jt * 16 + lane] = v;
  }
#pragma unroll
  for (int it = 0; it < 6; ++it)
#pragma unroll
    for (int r = 0; r < 4; ++r) {
      float v = rm[it][r];
      v = fmaxf(v, __shfl_xor(v, 1, 64));
      v = fmaxf(v, __shfl_xor(v, 2, 64));
      v = fmaxf(v, __shfl_xor(v, 4, 64));
      v = fmaxf(v, __shfl_xor(v, 8, 64));
      if (l15 == 0) rowpart[wj][wi * 96 + it * 16 + l4 * 4 + r] = v;
    }
  __syncthreads();

  // ---- fused BN -> fc -> lbn -> sigmoid ----
  float part = 0.f, wpart = 0.f;
  if (tid < HW) {
    float cmax = fmaxf(colpart[0][tid], colpart[1][tid]);  // score[j]
    float rmax = fmaxf(rowpart[0][tid], rowpart[1][tid]);  // score[192+i]
    float w1 = fcw[tid], w2 = fcw[HW + tid];
    part = cmax * w1 + rmax * w2;
    wpart = w1 + w2;
  }
#pragma unroll
  for (int off = 32; off > 0; off >>= 1) {
    part += __shfl_down(part, off, 64);
    wpart += __shfl_down(wpart, off, 64);
  }
  if (lane == 0) { redbuf[wave][0] = part; redbuf[wave][1] = wpart; }
  __syncthreads();
  if (tid == 0) {
    float s = redbuf[0][0] + redbuf[1][0] + redbuf[2][0] + redbuf[3][0];
    float wsum = redbuf[0][1] + redbuf[1][1] + redbuf[2][1] + redbuf[3][1];
    float bnA = bnw[0] * rsqrtf(bnv[0] + 1e-5f);
    float bnB = bnb[0] - bnm[0] * bnA;
    float sc = bnA * s + bnB * wsum + fcb[0];
    float lA = lw[0] * rsqrtf(lv[0] + 1e-5f);
    sc = (sc - lm[0]) * lA + lb[0];
    out[g * PP + p] = 1.f / (1.f + __expf(-sc * 0.1f));
  }
}

extern "C" void kernel_launch(void* const* d_in, const int* in_sizes, int n_in,
                              void* d_out, int out_size, void* d_ws, size_t ws_size,
                              hipStream_t stream) {
  const float* gal  = (const float*)d_in[0];
  const float* prob = (const float*)d_in[1];
  const float* bnw  = (const float*)d_in[2];
  const float* bnb  = (const float*)d_in[3];
  const float* bnm  = (const float*)d_in[4];
  const float* bnv  = (const float*)d_in[5];
  const float* fcw  = (const float*)d_in[6];
  const float* fcb  = (const float*)d_in[7];
  const float* lw   = (const float*)d_in[8];
  const float* lb   = (const float*)d_in[9];
  const float* lm   = (const float*)d_in[10];
  const float* lv   = (const float*)d_in[11];
  unsigned char* ws = (unsigned char*)d_ws;
  float* out = (float*)d_out;

  hipLaunchKernelGGL(norm_kernel, dim3(1536), dim3(512), 0, stream, gal, prob, ws);
  hipLaunchKernelGGL(qaconv_gemm, dim3(GG * PP), dim3(256), 0, stream, ws, fcw,
                     bnw, bnb, bnm, bnv, fcb, lw, lb, lm, lv, out);
}